// Round 9
// baseline (1419.647 us; speedup 1.0000x reference)
//
#include <hip/hip_runtime.h>
#include <hip/hip_bf16.h>

// 2-layer GIN. Radix-partition edges into 240-node buckets, then ONE fused
// kernel per layer: WG owns a bucket, accumulates agg for its 240 nodes in
// LDS (fp32, ds_add_f32) from bf16 gathers, then runs the MLP from LDS.
// Eliminates node-level sort (k4), esrc, and the fp32 A round-trip.
//   agg = f32(hb[n]) + sum f32(hb[src]);  h' = relu(agg @ W + b)
// n_nodes < 2^17 (18-bit src pack). N=100000, E=1600000, D=64.

#define D 64
#define NPBS 240       // nodes per bucket (LDS accum = 240*64*4 = 60 KiB)
#define NBSMAX 512     // static LDS cap on #buckets in k1/k3
#define CHSZ 8192      // edges per chunk (k1/k3)
#define MAXNCH 512     // static LDS cap on #chunks in k2c
#define MAGIC240 143165577ull   // ceil(2^35/240); exact floor(d/240) for d<3e8

typedef unsigned short ushort_t;

__device__ inline int bucket_of(int d) {
    return (int)(((unsigned long long)(unsigned)d * MAGIC240) >> 35);
}

__device__ inline unsigned short f2bf(float f) {   // RNE round to bf16
    unsigned u = __float_as_uint(f);
    return (unsigned short)((u + 0x7fff + ((u >> 16) & 1)) >> 16);
}

// unpack 32B of bf16 (2 uint4) into 16 floats
__device__ inline void unpack16(float* v, uint4 u0, uint4 u1) {
    v[0]  = __uint_as_float(u0.x << 16); v[1]  = __uint_as_float(u0.x & 0xffff0000u);
    v[2]  = __uint_as_float(u0.y << 16); v[3]  = __uint_as_float(u0.y & 0xffff0000u);
    v[4]  = __uint_as_float(u0.z << 16); v[5]  = __uint_as_float(u0.z & 0xffff0000u);
    v[6]  = __uint_as_float(u0.w << 16); v[7]  = __uint_as_float(u0.w & 0xffff0000u);
    v[8]  = __uint_as_float(u1.x << 16); v[9]  = __uint_as_float(u1.x & 0xffff0000u);
    v[10] = __uint_as_float(u1.y << 16); v[11] = __uint_as_float(u1.y & 0xffff0000u);
    v[12] = __uint_as_float(u1.z << 16); v[13] = __uint_as_float(u1.z & 0xffff0000u);
    v[14] = __uint_as_float(u1.w << 16); v[15] = __uint_as_float(u1.w & 0xffff0000u);
}

// ---------------- build ----------------

__global__ void zero_total(int* __restrict__ total, int nbs) {
    for (int j = threadIdx.x; j < nbs; j += 256) total[j] = 0;
}

// Per-chunk LDS histogram over buckets; also per-bucket totals.
__global__ __launch_bounds__(256) void k1_hist(const int* __restrict__ dst,
                                               int* __restrict__ hist,
                                               int* __restrict__ total,
                                               int n_edges, int nch, int nbs) {
    __shared__ int lh[NBSMAX];
    for (int i = threadIdx.x; i < nbs; i += 256) lh[i] = 0;
    __syncthreads();
    int base = blockIdx.x * CHSZ;
    int lim = min(CHSZ, n_edges - base);
    for (int k = threadIdx.x; k < lim; k += 256)
        atomicAdd(&lh[bucket_of(dst[base + k])], 1);
    __syncthreads();
    for (int i = threadIdx.x; i < nbs; i += 256) {
        int v = lh[i];
        hist[i * nch + blockIdx.x] = v;   // bucket-major
        if (v) atomicAdd(&total[i], v);
    }
}

// Single WG: exclusive scan of nbs (<= 512) bucket totals -> sstart.
__global__ __launch_bounds__(256) void k2b_scan(const int* __restrict__ total,
                                                int* __restrict__ sstart,
                                                int nbs, int n_edges) {
    __shared__ int tsum[256];
    int tid = threadIdx.x;
    int per = (nbs + 255) / 256;
    int b0 = tid * per;
    int s = 0;
    for (int i = 0; i < per; ++i)
        if (b0 + i < nbs) s += total[b0 + i];
    tsum[tid] = s;
    __syncthreads();
    for (int off = 1; off < 256; off <<= 1) {
        int v = (tid >= off) ? tsum[tid - off] : 0;
        __syncthreads();
        tsum[tid] += v;
        __syncthreads();
    }
    int run = (tid == 0) ? 0 : tsum[tid - 1];
    for (int i = 0; i < per; ++i) {
        int idx = b0 + i;
        if (idx < nbs) { sstart[idx] = run; run += total[idx]; }
    }
    if (tid == 255) sstart[nbs] = n_edges;
}

// One block per bucket: exclusive scan of its chunk-count row (+ sstart[b]).
__global__ __launch_bounds__(256) void k2c_rowscan(int* __restrict__ hist,
                                                   const int* __restrict__ sstart,
                                                   int nch, int nbs) {
    __shared__ int t[MAXNCH];
    int b = blockIdx.x;
    int tid = threadIdx.x;
    int* row = hist + (size_t)b * nch;
    int nround = (nch + 255) & ~255;
    for (int i = tid; i < nround; i += 256) t[i] = (i < nch) ? row[i] : 0;
    __syncthreads();
    for (int off = 1; off < nround; off <<= 1) {
        int v[MAXNCH / 256];
        for (int i = tid, j = 0; i < nround; i += 256, ++j)
            v[j] = (i >= off) ? t[i - off] : 0;
        __syncthreads();
        for (int i = tid, j = 0; i < nround; i += 256, ++j) t[i] += v[j];
        __syncthreads();
    }
    int base = sstart[b];
    for (int i = tid; i < nch; i += 256)
        row[i] = base + ((i == 0) ? 0 : t[i - 1]);
}

// Per-chunk scatter with LDS cursors -> tmp (packed local<<18 | src).
__global__ __launch_bounds__(256) void k3_scatter(const int* __restrict__ src,
                                                  const int* __restrict__ dst,
                                                  const int* __restrict__ hist,
                                                  unsigned* __restrict__ tmp,
                                                  int n_edges, int nch, int nbs) {
    __shared__ int lcur[NBSMAX];
    int c = blockIdx.x;
    for (int i = threadIdx.x; i < nbs; i += 256) lcur[i] = hist[i * nch + c];
    __syncthreads();
    int base = c * CHSZ;
    int lim = min(CHSZ, n_edges - base);
    for (int k = threadIdx.x; k < lim; k += 256) {
        int d = dst[base + k];
        int s = src[base + k];
        int bk = bucket_of(d);
        int local = d - bk * NPBS;
        int pos = atomicAdd(&lcur[bk], 1);
        tmp[pos] = ((unsigned)local << 18) | (unsigned)s;
    }
}

// ---------------- per-layer ----------------

__global__ __launch_bounds__(256) void to_bf16(const float4* __restrict__ in,
                                               uint2* __restrict__ out, int n4) {
    int i = blockIdx.x * 256 + threadIdx.x;
    if (i >= n4) return;
    float4 v = in[i];
    out[i] = make_uint2((unsigned)f2bf(v.x) | ((unsigned)f2bf(v.y) << 16),
                        (unsigned)f2bf(v.z) | ((unsigned)f2bf(v.w) << 16));
}

// Fused layer: WG (1024 thr) owns one 240-node bucket.
//  phase A: self-term init of LDS accum (bank-rotated layout).
//  phase B: edge loop — 4 lanes/edge gather 32B bf16 each, ds_add_f32 into
//           accum[local] with per-node rotation (e+local)&15 (breaks the
//           all-lanes-same-bank pattern: node*64 % 32 == 0).
//  phase C: MLP from LDS; W/bias from global (L1-resident, 16KB);
//           relu; coalesced row writes.
// Stored column for true col k of row r: (k & ~15) + (((k&15) + r) & 15).
template <bool BF16OUT>
__global__ __launch_bounds__(1024, 8) void gin_fused(const uint4* __restrict__ hb,
                                                     const unsigned* __restrict__ tmp,
                                                     const int* __restrict__ sstart,
                                                     const float* __restrict__ W,
                                                     const float* __restrict__ bias,
                                                     void* __restrict__ out_,
                                                     int n_nodes) {
    __shared__ float accum[NPBS * D];   // 61440 B

    int b = blockIdx.x;
    int t = threadIdx.x;
    int c = t & 3;          // 32B chunk of the 128B bf16 row
    int slot = t >> 2;      // edge/node slot 0..255
    int node0 = b * NPBS;
    int nvalid = min(NPBS, n_nodes - node0);

    // ---- phase A: self-term init (slot = local node id) ----
    if (slot < NPBS) {
        float v[16];
        if (slot < nvalid) {
            uint4 u0 = hb[(size_t)(node0 + slot) * 8 + c * 2];
            uint4 u1 = hb[(size_t)(node0 + slot) * 8 + c * 2 + 1];
            unpack16(v, u0, u1);
        } else {
#pragma unroll
            for (int e = 0; e < 16; ++e) v[e] = 0.0f;
        }
        float* row = accum + slot * D + c * 16;
#pragma unroll
        for (int e = 0; e < 16; ++e) row[(e + slot) & 15] = v[e];
    }
    __syncthreads();

    // ---- phase B: edge accumulation ----
    int base = sstart[b];
    int cnt = sstart[b + 1] - base;
    for (int i = slot; i < cnt; i += 256) {
        unsigned p = tmp[base + i];
        int local = (int)(p >> 18) & 255;
        int s = (int)(p & 0x3FFFFu);
        uint4 u0 = hb[(size_t)s * 8 + c * 2];
        uint4 u1 = hb[(size_t)s * 8 + c * 2 + 1];
        float v[16];
        unpack16(v, u0, u1);
        float* row = accum + local * D + c * 16;
#pragma unroll
        for (int e = 0; e < 16; ++e)
            atomicAdd(&row[(e + local) & 15], v[e]);
    }
    __syncthreads();

    // ---- phase C: MLP (15 active waves x 16 rows) ----
    int w = t >> 6;
    int lane = t & 63;
    if (w * 16 < NPBS) {
        float acc[16];
        float bv = bias[lane];
#pragma unroll
        for (int j = 0; j < 16; ++j) acc[j] = bv;
        for (int k = 0; k < D; ++k) {
            float wv = W[k * D + lane];     // L1-hit broadcast-ish
            int cc = k & ~15, ee = k & 15;
#pragma unroll
            for (int j = 0; j < 16; ++j) {
                int r = w * 16 + j;
                acc[j] = fmaf(accum[r * D + cc + ((ee + r) & 15)], wv, acc[j]);
            }
        }
#pragma unroll
        for (int j = 0; j < 16; ++j) {
            int r = w * 16 + j;
            if (r < nvalid) {
                float vv = acc[j] > 0.0f ? acc[j] : 0.0f;
                size_t idx = (size_t)(node0 + r) * D + lane;
                if (BF16OUT) ((ushort_t*)out_)[idx] = f2bf(vv);
                else         ((float*)out_)[idx] = vv;
            }
        }
    }
}

extern "C" void kernel_launch(void* const* d_in, const int* in_sizes, int n_in,
                              void* d_out, int out_size, void* d_ws, size_t ws_size,
                              hipStream_t stream) {
    const float* x   = (const float*)d_in[0];
    const int*   src = (const int*)d_in[1];
    const int*   dst = (const int*)d_in[2];
    const float* W1  = (const float*)d_in[3];
    const float* b1  = (const float*)d_in[4];
    const float* W2  = (const float*)d_in[5];
    const float* b2  = (const float*)d_in[6];
    float* out = (float*)d_out;

    const int n_nodes = in_sizes[0] / D;
    const int n_edges = in_sizes[1];
    const int nch = (n_edges + CHSZ - 1) / CHSZ;        // 196
    const int nbs = (n_nodes + NPBS - 1) / NPBS;        // 417

    // workspace: xb | h1b | sstart | total | hist | tmp   (~32.5 MB)
    ushort_t* xb     = (ushort_t*)d_ws;                       // n_nodes*64 bf16
    ushort_t* h1b    = xb + (size_t)n_nodes * D;              // n_nodes*64 bf16
    int*      sstart = (int*)(h1b + (size_t)n_nodes * D);     // nbs+1
    int*      total  = sstart + (nbs + 1);                    // nbs
    int*      hist   = total + nbs;                           // nbs*nch
    unsigned* tmp    = (unsigned*)(hist + (size_t)nbs * nch); // n_edges

    const int cvt_blocks = (n_nodes * (D / 4) + 255) / 256;

    // ---- build ----
    zero_total<<<1, 256, 0, stream>>>(total, nbs);
    to_bf16<<<cvt_blocks, 256, 0, stream>>>((const float4*)x, (uint2*)xb,
                                            n_nodes * (D / 4));
    k1_hist<<<nch, 256, 0, stream>>>(dst, hist, total, n_edges, nch, nbs);
    k2b_scan<<<1, 256, 0, stream>>>(total, sstart, nbs, n_edges);
    k2c_rowscan<<<nbs, 256, 0, stream>>>(hist, sstart, nch, nbs);
    k3_scatter<<<nch, 256, 0, stream>>>(src, dst, hist, tmp, n_edges, nch, nbs);

    // ---- layer 1: fused agg+mlp, xb -> h1b (bf16) ----
    gin_fused<true><<<nbs, 1024, 0, stream>>>((const uint4*)xb, tmp, sstart,
                                              W1, b1, h1b, n_nodes);
    // ---- layer 2: fused agg+mlp, h1b -> out (fp32) ----
    gin_fused<false><<<nbs, 1024, 0, stream>>>((const uint4*)h1b, tmp, sstart,
                                               W2, b2, out, n_nodes);
}

// Round 10
// 195.192 us; speedup vs baseline: 7.2731x; 7.2731x over previous
//
#include <hip/hip_runtime.h>
#include <hip/hip_bf16.h>

// 2-layer GIN, pull-mode aggregation, bf16 feature AND bf16 agg matrices.
//   aggb = bf16( f32(hb[n]) + sum f32(hb[src]) );  h' = relu(agg @ W + b)
// Structure = R6 (best: 196us): radix-partition CSR build + separate lean
// agg (36 VGPR) / mlp kernels. R7/R9 fusions and R8 degree-perm all regressed.
// This round: bf16 A-matrix, k2b folded into k2c, zero folded into cvt.
// Requires n_nodes <= 131072 (18-bit src pack, 256-bucket scans).

#define D 64
#define ROWS_PER_BLOCK 32
#define CHSZ 8192      // edges per chunk (k1/k3)
#define NPBS 512       // nodes per super-bucket
#define SBSHIFT 9      // log2(NPBS)
#define MAXNBS 256     // static cap on #super-buckets (n_nodes <= 131072)
#define MAXNCH 512     // static cap on #chunks in k2c (n_edges <= 4.2M)

typedef unsigned short ushort_t;

__device__ inline unsigned short f2bf(float f) {   // RNE round to bf16
    unsigned u = __float_as_uint(f);
    return (unsigned short)((u + 0x7fff + ((u >> 16) & 1)) >> 16);
}

// acc[0..7] += 8 bf16 unpacked from one uint4
__device__ inline void acc8(float* acc, uint4 v) {
    acc[0] += __uint_as_float(v.x << 16);
    acc[1] += __uint_as_float(v.x & 0xffff0000u);
    acc[2] += __uint_as_float(v.y << 16);
    acc[3] += __uint_as_float(v.y & 0xffff0000u);
    acc[4] += __uint_as_float(v.z << 16);
    acc[5] += __uint_as_float(v.z & 0xffff0000u);
    acc[6] += __uint_as_float(v.w << 16);
    acc[7] += __uint_as_float(v.w & 0xffff0000u);
}

// 8 floats from one uint4 of packed bf16
__device__ inline void unpack8(float* v, uint4 u) {
    v[0] = __uint_as_float(u.x << 16); v[1] = __uint_as_float(u.x & 0xffff0000u);
    v[2] = __uint_as_float(u.y << 16); v[3] = __uint_as_float(u.y & 0xffff0000u);
    v[4] = __uint_as_float(u.z << 16); v[5] = __uint_as_float(u.z & 0xffff0000u);
    v[6] = __uint_as_float(u.w << 16); v[7] = __uint_as_float(u.w & 0xffff0000u);
}

// ---------------- CSR build ----------------

// fp32 -> bf16 conversion; block 0 also zeros the bucket totals.
__global__ __launch_bounds__(256) void to_bf16z(const float4* __restrict__ in,
                                                uint2* __restrict__ out, int n4,
                                                int* __restrict__ total, int nbs) {
    int i = blockIdx.x * 256 + threadIdx.x;
    if (blockIdx.x == 0)
        for (int j = threadIdx.x; j < nbs; j += 256) total[j] = 0;
    if (i >= n4) return;
    float4 v = in[i];
    out[i] = make_uint2((unsigned)f2bf(v.x) | ((unsigned)f2bf(v.y) << 16),
                        (unsigned)f2bf(v.z) | ((unsigned)f2bf(v.w) << 16));
}

// Per-chunk LDS histogram over super-buckets; accumulates per-bucket totals.
__global__ __launch_bounds__(256) void k1_hist(const int* __restrict__ dst,
                                               int* __restrict__ hist,
                                               int* __restrict__ total,
                                               int n_edges, int nch, int nbs) {
    __shared__ int lh[MAXNBS];
    for (int i = threadIdx.x; i < nbs; i += 256) lh[i] = 0;
    __syncthreads();
    int base = blockIdx.x * CHSZ;
    int lim = min(CHSZ, n_edges - base);
    for (int k = threadIdx.x; k < lim; k += 256)
        atomicAdd(&lh[dst[base + k] >> SBSHIFT], 1);
    __syncthreads();
    for (int i = threadIdx.x; i < nbs; i += 256) {
        int v = lh[i];
        hist[i * nch + blockIdx.x] = v;   // bucket-major
        if (v) atomicAdd(&total[i], v);
    }
}

// One block per bucket: (a) block-local prefix over the <=256 bucket totals
// gives this bucket's base (k2b folded in); (b) exclusive scan of its
// chunk-count row (+ base), in place; writes sstart[b].
__global__ __launch_bounds__(256) void k2c_rowscan(int* __restrict__ hist,
                                                   const int* __restrict__ total,
                                                   int* __restrict__ sstart,
                                                   int nch, int nbs, int n_edges) {
    __shared__ int tt[256];
    __shared__ int t[MAXNCH];
    int b = blockIdx.x;
    int tid = threadIdx.x;

    // (a) inclusive Hillis scan of totals
    tt[tid] = (tid < nbs) ? total[tid] : 0;
    __syncthreads();
    for (int off = 1; off < 256; off <<= 1) {
        int v = (tid >= off) ? tt[tid - off] : 0;
        __syncthreads();
        tt[tid] += v;
        __syncthreads();
    }
    int base = (b == 0) ? 0 : tt[b - 1];
    if (tid == 0) {
        sstart[b] = base;
        if (b == 0) sstart[nbs] = n_edges;
    }

    // (b) row scan
    int* row = hist + (size_t)b * nch;
    int nround = (nch + 255) & ~255;
    for (int i = tid; i < nround; i += 256) t[i] = (i < nch) ? row[i] : 0;
    __syncthreads();
    for (int off = 1; off < nround; off <<= 1) {
        int v[MAXNCH / 256];
        for (int i = tid, j = 0; i < nround; i += 256, ++j)
            v[j] = (i >= off) ? t[i - off] : 0;
        __syncthreads();
        for (int i = tid, j = 0; i < nround; i += 256, ++j) t[i] += v[j];
        __syncthreads();
    }
    for (int i = tid; i < nch; i += 256)
        row[i] = base + ((i == 0) ? 0 : t[i - 1]);
}

__global__ __launch_bounds__(256) void k3_scatter(const int* __restrict__ src,
                                                  const int* __restrict__ dst,
                                                  const int* __restrict__ hist,
                                                  unsigned* __restrict__ tmp,
                                                  int n_edges, int nch, int nbs) {
    __shared__ int lcur[MAXNBS];
    int c = blockIdx.x;
    for (int i = threadIdx.x; i < nbs; i += 256) lcur[i] = hist[i * nch + c];
    __syncthreads();
    int base = c * CHSZ;
    int lim = min(CHSZ, n_edges - base);
    for (int k = threadIdx.x; k < lim; k += 256) {
        int d = dst[base + k];
        int s = src[base + k];
        int pos = atomicAdd(&lcur[d >> SBSHIFT], 1);
        tmp[pos] = ((unsigned)(d & (NPBS - 1)) << 18) | (unsigned)s;
    }
}

// One WG per super-bucket: node-level counting sort in a WG-owned window.
__global__ __launch_bounds__(256) void k4_fine(const unsigned* __restrict__ tmp,
                                               const int* __restrict__ sstart,
                                               int* __restrict__ esrc,
                                               int* __restrict__ offs,
                                               int n_nodes) {
    __shared__ int lcnt[NPBS];
    __shared__ int lcur[NPBS];
    __shared__ int tsum[256];

    int b = blockIdx.x;
    int tid = threadIdx.x;
    int base = sstart[b];
    int cnt = sstart[b + 1] - base;

    lcnt[tid] = 0; lcnt[tid + 256] = 0;
    __syncthreads();

    for (int i = tid; i < cnt; i += 256)
        atomicAdd(&lcnt[tmp[base + i] >> 18], 1);
    __syncthreads();

    int a0 = lcnt[2 * tid], a1 = lcnt[2 * tid + 1];
    tsum[tid] = a0 + a1;
    __syncthreads();
    for (int off = 1; off < 256; off <<= 1) {
        int v = (tid >= off) ? tsum[tid - off] : 0;
        __syncthreads();
        tsum[tid] += v;
        __syncthreads();
    }
    int ex = (tid == 0) ? 0 : tsum[tid - 1];
    lcur[2 * tid] = ex;
    lcur[2 * tid + 1] = ex + a0;

    int node = b * NPBS + 2 * tid;
    if (node <= n_nodes) offs[node] = base + ex;
    if (node + 1 <= n_nodes) offs[node + 1] = base + ex + a0;
    __syncthreads();

    for (int i = tid; i < cnt; i += 256) {
        unsigned p = tmp[base + i];
        int pos = atomicAdd(&lcur[p >> 18], 1);
        esrc[base + pos] = (int)(p & 0x3FFFFu);
    }
}

// ---------------- per-layer kernels ----------------

// Pull aggregation over bf16 matrix: 4 lanes/node, lane c owns bf16 cols
// [c*16, c*16+16) = 2 uint4. acc starts at hb[n] (self term, eps=0).
// Output agg is ALSO bf16 (2 uint4 per lane).
__global__ __launch_bounds__(256) void gin_agg_bf(const uint4* __restrict__ hb,
                                                  const int* __restrict__ offs,
                                                  const int* __restrict__ esrc,
                                                  uint4* __restrict__ aggb,
                                                  int n_nodes) {
    int t = blockIdx.x * 256 + threadIdx.x;
    int n = t >> 2;
    if (n >= n_nodes) return;
    int c = t & 3;
    const uint4* self = hb + (size_t)n * 8 + c * 2;   // row = 8 uint4 (128 B)
    float acc[16];
#pragma unroll
    for (int j = 0; j < 16; ++j) acc[j] = 0.0f;
    uint4 sv0 = self[0], sv1 = self[1];
    acc8(acc, sv0); acc8(acc + 8, sv1);

    int i = offs[n];
    int end = offs[n + 1];
    for (; i + 4 <= end; i += 4) {
        const uint4* r0 = hb + (size_t)esrc[i]     * 8 + c * 2;
        const uint4* r1 = hb + (size_t)esrc[i + 1] * 8 + c * 2;
        const uint4* r2 = hb + (size_t)esrc[i + 2] * 8 + c * 2;
        const uint4* r3 = hb + (size_t)esrc[i + 3] * 8 + c * 2;
        uint4 a0 = r0[0], b0 = r0[1];
        uint4 a1 = r1[0], b1 = r1[1];
        uint4 a2 = r2[0], b2 = r2[1];
        uint4 a3 = r3[0], b3 = r3[1];
        acc8(acc, a0); acc8(acc + 8, b0);
        acc8(acc, a1); acc8(acc + 8, b1);
        acc8(acc, a2); acc8(acc + 8, b2);
        acc8(acc, a3); acc8(acc + 8, b3);
    }
    for (; i < end; ++i) {
        const uint4* r = hb + (size_t)esrc[i] * 8 + c * 2;
        uint4 a = r[0], b = r[1];
        acc8(acc, a); acc8(acc + 8, b);
    }

    uint4 o0, o1;
    o0.x = (unsigned)f2bf(acc[0])  | ((unsigned)f2bf(acc[1])  << 16);
    o0.y = (unsigned)f2bf(acc[2])  | ((unsigned)f2bf(acc[3])  << 16);
    o0.z = (unsigned)f2bf(acc[4])  | ((unsigned)f2bf(acc[5])  << 16);
    o0.w = (unsigned)f2bf(acc[6])  | ((unsigned)f2bf(acc[7])  << 16);
    o1.x = (unsigned)f2bf(acc[8])  | ((unsigned)f2bf(acc[9])  << 16);
    o1.y = (unsigned)f2bf(acc[10]) | ((unsigned)f2bf(acc[11]) << 16);
    o1.z = (unsigned)f2bf(acc[12]) | ((unsigned)f2bf(acc[13]) << 16);
    o1.w = (unsigned)f2bf(acc[14]) | ((unsigned)f2bf(acc[15]) << 16);
    aggb[(size_t)n * 8 + c * 2]     = o0;
    aggb[(size_t)n * 8 + c * 2 + 1] = o1;
}

// out = relu(hs @ W + b); hs is bf16 (uint4-packed), staged to fp32 LDS.
// BF16OUT selects bf16 or fp32 output.
#define RSTRIDE (D + 4)   // padded LDS row stride (bank-spread)
template <bool BF16OUT>
__global__ __launch_bounds__(256) void gin_mlp(const uint4* __restrict__ hs,
                                               const float* __restrict__ W,
                                               const float* __restrict__ b,
                                               void* __restrict__ out_,
                                               int n_nodes) {
    __shared__ float Wl[D * D];
    __shared__ float bl[D];
    __shared__ float rows[ROWS_PER_BLOCK * RSTRIDE];

    int tid = threadIdx.x;

    const float4* W4 = (const float4*)W;
    float4* Wl4 = (float4*)Wl;
#pragma unroll
    for (int i = 0; i < 4; ++i) Wl4[tid + 256 * i] = W4[tid + 256 * i];
    if (tid < D / 4) ((float4*)bl)[tid] = ((const float4*)b)[tid];

    // stage 32 bf16 rows -> fp32 LDS (1 uint4 = 8 elems per thread)
    size_t row0 = (size_t)blockIdx.x * ROWS_PER_BLOCK;
    {
        uint4 u = hs[row0 * 8 + tid];
        float v[8];
        unpack8(v, u);
        int r = tid >> 3;            // 8 uint4 per 64-col row
        int col = (tid & 7) * 8;
        float* dstp = rows + r * RSTRIDE + col;
#pragma unroll
        for (int j = 0; j < 8; ++j) dstp[j] = v[j];
    }
    __syncthreads();

    int lane = tid & 63;
    int w = tid >> 6;

    float acc[8];
#pragma unroll
    for (int r = 0; r < 8; ++r) acc[r] = bl[lane];

#pragma unroll
    for (int k = 0; k < D; ++k) {
        float wv = Wl[k * D + lane];
#pragma unroll
        for (int r = 0; r < 8; ++r)
            acc[r] = fmaf(rows[(w * 8 + r) * RSTRIDE + k], wv, acc[r]);
    }

#pragma unroll
    for (int r = 0; r < 8; ++r) {
        float v = acc[r] > 0.0f ? acc[r] : 0.0f;
        size_t idx = (row0 + (size_t)w * 8 + r) * D + lane;
        if (BF16OUT) ((ushort_t*)out_)[idx] = f2bf(v);
        else         ((float*)out_)[idx] = v;
    }
}

extern "C" void kernel_launch(void* const* d_in, const int* in_sizes, int n_in,
                              void* d_out, int out_size, void* d_ws, size_t ws_size,
                              hipStream_t stream) {
    const float* x   = (const float*)d_in[0];
    const int*   src = (const int*)d_in[1];
    const int*   dst = (const int*)d_in[2];
    const float* W1  = (const float*)d_in[3];
    const float* b1  = (const float*)d_in[4];
    const float* W2  = (const float*)d_in[5];
    const float* b2  = (const float*)d_in[6];
    float* out = (float*)d_out;

    const int n_nodes = in_sizes[0] / D;
    const int n_edges = in_sizes[1];
    const int nch = (n_edges + CHSZ - 1) / CHSZ;     // 196
    const int nbs = (n_nodes + NPBS - 1) / NPBS;     // 196

    // workspace: Ab(bf16) | hb(bf16) | offs | sstart | total | hist | tmp | esrc
    ushort_t* Ab     = (ushort_t*)d_ws;                       // n_nodes*64 bf16
    ushort_t* hb     = Ab + (size_t)n_nodes * D;              // n_nodes*64 bf16
    int*      offs   = (int*)(hb + (size_t)n_nodes * D);      // n_nodes+1
    int*      sstart = offs + (n_nodes + 1);                  // nbs+1
    int*      total  = sstart + (nbs + 1);                    // nbs
    int*      hist   = total + nbs;                           // nbs*nch
    unsigned* tmp    = (unsigned*)(hist + (size_t)nbs * nch); // n_edges
    int*      esrc   = (int*)(tmp + n_edges);                 // n_edges

    const int agg_blocks = (n_nodes * 4 + 255) / 256;
    const int mlp_blocks = (n_nodes + ROWS_PER_BLOCK - 1) / ROWS_PER_BLOCK;
    const int cvt_blocks = (n_nodes * (D / 4) + 255) / 256;

    // ---- CSR build (9 dispatches total this launch) ----
    to_bf16z<<<cvt_blocks, 256, 0, stream>>>((const float4*)x, (uint2*)hb,
                                             n_nodes * (D / 4), total, nbs);
    k1_hist<<<nch, 256, 0, stream>>>(dst, hist, total, n_edges, nch, nbs);
    k2c_rowscan<<<nbs, 256, 0, stream>>>(hist, total, sstart, nch, nbs, n_edges);
    k3_scatter<<<nch, 256, 0, stream>>>(src, dst, hist, tmp, n_edges, nch, nbs);
    k4_fine<<<nbs, 256, 0, stream>>>(tmp, sstart, esrc, offs, n_nodes);

    // ---- layer 1: agg(xb) -> Ab; mlp(Ab) -> hb (bf16 h1) ----
    gin_agg_bf<<<agg_blocks, 256, 0, stream>>>((const uint4*)hb, offs, esrc,
                                               (uint4*)Ab, n_nodes);
    gin_mlp<true><<<mlp_blocks, 256, 0, stream>>>((const uint4*)Ab, W1, b1,
                                                  hb, n_nodes);

    // ---- layer 2: agg(h1b) -> Ab; mlp(Ab) -> out (fp32) ----
    gin_agg_bf<<<agg_blocks, 256, 0, stream>>>((const uint4*)hb, offs, esrc,
                                               (uint4*)Ab, n_nodes);
    gin_mlp<false><<<mlp_blocks, 256, 0, stream>>>((const uint4*)Ab, W2, b2,
                                                   out, n_nodes);
}

// Round 11
// 191.459 us; speedup vs baseline: 7.4149x; 1.0195x over previous
//
#include <hip/hip_runtime.h>
#include <hip/hip_bf16.h>

// 2-layer GIN, pull-mode aggregation, bf16 feature AND bf16 agg matrices.
//   aggb = bf16( f32(hb[n]) + sum f32(hb[src]) );  h' = relu(agg @ W + b)
// R11: agg inner loop unrolled 8x (16 uint4 in flight / thread) to attack the
// latency*MLP bound seen in R10 (VALUBusy 4.5%, occ 45%, 2.9 TB/s effective).
// esrc stores src*8 (uint4 row base). 128-thread agg blocks.
// Requires n_nodes <= 131072 (18-bit src pack, 256-bucket scans).

#define D 64
#define ROWS_PER_BLOCK 32
#define CHSZ 8192      // edges per chunk (k1/k3)
#define NPBS 512       // nodes per super-bucket
#define SBSHIFT 9      // log2(NPBS)
#define MAXNBS 256     // static cap on #super-buckets (n_nodes <= 131072)
#define MAXNCH 512     // static cap on #chunks in k2c (n_edges <= 4.2M)

typedef unsigned short ushort_t;

__device__ inline unsigned short f2bf(float f) {   // RNE round to bf16
    unsigned u = __float_as_uint(f);
    return (unsigned short)((u + 0x7fff + ((u >> 16) & 1)) >> 16);
}

// acc[0..7] += 8 bf16 unpacked from one uint4
__device__ inline void acc8(float* acc, uint4 v) {
    acc[0] += __uint_as_float(v.x << 16);
    acc[1] += __uint_as_float(v.x & 0xffff0000u);
    acc[2] += __uint_as_float(v.y << 16);
    acc[3] += __uint_as_float(v.y & 0xffff0000u);
    acc[4] += __uint_as_float(v.z << 16);
    acc[5] += __uint_as_float(v.z & 0xffff0000u);
    acc[6] += __uint_as_float(v.w << 16);
    acc[7] += __uint_as_float(v.w & 0xffff0000u);
}

// 8 floats from one uint4 of packed bf16
__device__ inline void unpack8(float* v, uint4 u) {
    v[0] = __uint_as_float(u.x << 16); v[1] = __uint_as_float(u.x & 0xffff0000u);
    v[2] = __uint_as_float(u.y << 16); v[3] = __uint_as_float(u.y & 0xffff0000u);
    v[4] = __uint_as_float(u.z << 16); v[5] = __uint_as_float(u.z & 0xffff0000u);
    v[6] = __uint_as_float(u.w << 16); v[7] = __uint_as_float(u.w & 0xffff0000u);
}

// ---------------- CSR build ----------------

// fp32 -> bf16 conversion; block 0 also zeros the bucket totals.
__global__ __launch_bounds__(256) void to_bf16z(const float4* __restrict__ in,
                                                uint2* __restrict__ out, int n4,
                                                int* __restrict__ total, int nbs) {
    int i = blockIdx.x * 256 + threadIdx.x;
    if (blockIdx.x == 0)
        for (int j = threadIdx.x; j < nbs; j += 256) total[j] = 0;
    if (i >= n4) return;
    float4 v = in[i];
    out[i] = make_uint2((unsigned)f2bf(v.x) | ((unsigned)f2bf(v.y) << 16),
                        (unsigned)f2bf(v.z) | ((unsigned)f2bf(v.w) << 16));
}

// Per-chunk LDS histogram over super-buckets; accumulates per-bucket totals.
__global__ __launch_bounds__(256) void k1_hist(const int* __restrict__ dst,
                                               int* __restrict__ hist,
                                               int* __restrict__ total,
                                               int n_edges, int nch, int nbs) {
    __shared__ int lh[MAXNBS];
    for (int i = threadIdx.x; i < nbs; i += 256) lh[i] = 0;
    __syncthreads();
    int base = blockIdx.x * CHSZ;
    int lim = min(CHSZ, n_edges - base);
    for (int k = threadIdx.x; k < lim; k += 256)
        atomicAdd(&lh[dst[base + k] >> SBSHIFT], 1);
    __syncthreads();
    for (int i = threadIdx.x; i < nbs; i += 256) {
        int v = lh[i];
        hist[i * nch + blockIdx.x] = v;   // bucket-major
        if (v) atomicAdd(&total[i], v);
    }
}

// One block per bucket: (a) block-local prefix over the <=256 bucket totals
// gives this bucket's base (k2b folded in); (b) exclusive scan of its
// chunk-count row (+ base), in place; writes sstart[b].
__global__ __launch_bounds__(256) void k2c_rowscan(int* __restrict__ hist,
                                                   const int* __restrict__ total,
                                                   int* __restrict__ sstart,
                                                   int nch, int nbs, int n_edges) {
    __shared__ int tt[256];
    __shared__ int t[MAXNCH];
    int b = blockIdx.x;
    int tid = threadIdx.x;

    // (a) inclusive Hillis scan of totals
    tt[tid] = (tid < nbs) ? total[tid] : 0;
    __syncthreads();
    for (int off = 1; off < 256; off <<= 1) {
        int v = (tid >= off) ? tt[tid - off] : 0;
        __syncthreads();
        tt[tid] += v;
        __syncthreads();
    }
    int base = (b == 0) ? 0 : tt[b - 1];
    if (tid == 0) {
        sstart[b] = base;
        if (b == 0) sstart[nbs] = n_edges;
    }

    // (b) row scan
    int* row = hist + (size_t)b * nch;
    int nround = (nch + 255) & ~255;
    for (int i = tid; i < nround; i += 256) t[i] = (i < nch) ? row[i] : 0;
    __syncthreads();
    for (int off = 1; off < nround; off <<= 1) {
        int v[MAXNCH / 256];
        for (int i = tid, j = 0; i < nround; i += 256, ++j)
            v[j] = (i >= off) ? t[i - off] : 0;
        __syncthreads();
        for (int i = tid, j = 0; i < nround; i += 256, ++j) t[i] += v[j];
        __syncthreads();
    }
    for (int i = tid; i < nch; i += 256)
        row[i] = base + ((i == 0) ? 0 : t[i - 1]);
}

__global__ __launch_bounds__(256) void k3_scatter(const int* __restrict__ src,
                                                  const int* __restrict__ dst,
                                                  const int* __restrict__ hist,
                                                  unsigned* __restrict__ tmp,
                                                  int n_edges, int nch, int nbs) {
    __shared__ int lcur[MAXNBS];
    int c = blockIdx.x;
    for (int i = threadIdx.x; i < nbs; i += 256) lcur[i] = hist[i * nch + c];
    __syncthreads();
    int base = c * CHSZ;
    int lim = min(CHSZ, n_edges - base);
    for (int k = threadIdx.x; k < lim; k += 256) {
        int d = dst[base + k];
        int s = src[base + k];
        int pos = atomicAdd(&lcur[d >> SBSHIFT], 1);
        tmp[pos] = ((unsigned)(d & (NPBS - 1)) << 18) | (unsigned)s;
    }
}

// One WG per super-bucket: node-level counting sort in a WG-owned window.
// esrc entries are PRE-SCALED: value = src * 8 (uint4 index of the row base).
__global__ __launch_bounds__(256) void k4_fine(const unsigned* __restrict__ tmp,
                                               const int* __restrict__ sstart,
                                               int* __restrict__ esrc,
                                               int* __restrict__ offs,
                                               int n_nodes) {
    __shared__ int lcnt[NPBS];
    __shared__ int lcur[NPBS];
    __shared__ int tsum[256];

    int b = blockIdx.x;
    int tid = threadIdx.x;
    int base = sstart[b];
    int cnt = sstart[b + 1] - base;

    lcnt[tid] = 0; lcnt[tid + 256] = 0;
    __syncthreads();

    for (int i = tid; i < cnt; i += 256)
        atomicAdd(&lcnt[tmp[base + i] >> 18], 1);
    __syncthreads();

    int a0 = lcnt[2 * tid], a1 = lcnt[2 * tid + 1];
    tsum[tid] = a0 + a1;
    __syncthreads();
    for (int off = 1; off < 256; off <<= 1) {
        int v = (tid >= off) ? tsum[tid - off] : 0;
        __syncthreads();
        tsum[tid] += v;
        __syncthreads();
    }
    int ex = (tid == 0) ? 0 : tsum[tid - 1];
    lcur[2 * tid] = ex;
    lcur[2 * tid + 1] = ex + a0;

    int node = b * NPBS + 2 * tid;
    if (node <= n_nodes) offs[node] = base + ex;
    if (node + 1 <= n_nodes) offs[node + 1] = base + ex + a0;
    __syncthreads();

    for (int i = tid; i < cnt; i += 256) {
        unsigned p = tmp[base + i];
        int pos = atomicAdd(&lcur[p >> 18], 1);
        esrc[base + pos] = (int)((p & 0x3FFFFu) << 3);   // src*8
    }
}

// ---------------- per-layer kernels ----------------

// Pull aggregation over bf16 matrix: 4 lanes/node, lane c owns bf16 cols
// [c*16, c*16+16) = 2 uint4. Edge loop unrolled 8x: 16 uint4 loads in
// flight per thread (latency-bound regime, R10 post-mortem). acc starts at
// hb[n] (self term, eps=0). Output agg is bf16 (2 uint4 per lane).
__global__ __launch_bounds__(128) void gin_agg_bf(const uint4* __restrict__ hb,
                                                  const int* __restrict__ offs,
                                                  const int* __restrict__ esrc,
                                                  uint4* __restrict__ aggb,
                                                  int n_nodes) {
    int t = blockIdx.x * 128 + threadIdx.x;
    int n = t >> 2;
    if (n >= n_nodes) return;
    int c2 = (t & 3) * 2;
    const uint4* selfp = hb + (size_t)n * 8 + c2;   // row = 8 uint4 (128 B)
    float acc[16];
#pragma unroll
    for (int j = 0; j < 16; ++j) acc[j] = 0.0f;
    {
        uint4 s0 = selfp[0], s1 = selfp[1];
        acc8(acc, s0); acc8(acc + 8, s1);
    }

    int i = offs[n];
    int end = offs[n + 1];

    // 8-edge unrolled main loop: 16 uint4 gathers issued before any use.
    for (; i + 8 <= end; i += 8) {
        uint4 v[16];
#pragma unroll
        for (int j = 0; j < 8; ++j) {
            const uint4* r = hb + (size_t)(unsigned)esrc[i + j] + c2;
            v[2 * j]     = r[0];
            v[2 * j + 1] = r[1];
        }
#pragma unroll
        for (int j = 0; j < 8; ++j) {
            acc8(acc, v[2 * j]);
            acc8(acc + 8, v[2 * j + 1]);
        }
    }
    // 4-edge tail
    if (i + 4 <= end) {
        uint4 v[8];
#pragma unroll
        for (int j = 0; j < 4; ++j) {
            const uint4* r = hb + (size_t)(unsigned)esrc[i + j] + c2;
            v[2 * j]     = r[0];
            v[2 * j + 1] = r[1];
        }
#pragma unroll
        for (int j = 0; j < 4; ++j) {
            acc8(acc, v[2 * j]);
            acc8(acc + 8, v[2 * j + 1]);
        }
        i += 4;
    }
    // singles
    for (; i < end; ++i) {
        const uint4* r = hb + (size_t)(unsigned)esrc[i] + c2;
        uint4 a = r[0], b = r[1];
        acc8(acc, a); acc8(acc + 8, b);
    }

    uint4 o0, o1;
    o0.x = (unsigned)f2bf(acc[0])  | ((unsigned)f2bf(acc[1])  << 16);
    o0.y = (unsigned)f2bf(acc[2])  | ((unsigned)f2bf(acc[3])  << 16);
    o0.z = (unsigned)f2bf(acc[4])  | ((unsigned)f2bf(acc[5])  << 16);
    o0.w = (unsigned)f2bf(acc[6])  | ((unsigned)f2bf(acc[7])  << 16);
    o1.x = (unsigned)f2bf(acc[8])  | ((unsigned)f2bf(acc[9])  << 16);
    o1.y = (unsigned)f2bf(acc[10]) | ((unsigned)f2bf(acc[11]) << 16);
    o1.z = (unsigned)f2bf(acc[12]) | ((unsigned)f2bf(acc[13]) << 16);
    o1.w = (unsigned)f2bf(acc[14]) | ((unsigned)f2bf(acc[15]) << 16);
    aggb[(size_t)n * 8 + c2]     = o0;
    aggb[(size_t)n * 8 + c2 + 1] = o1;
}

// out = relu(hs @ W + b); hs is bf16 (uint4-packed), staged to fp32 LDS.
#define RSTRIDE (D + 4)   // padded LDS row stride (bank-spread)
template <bool BF16OUT>
__global__ __launch_bounds__(256) void gin_mlp(const uint4* __restrict__ hs,
                                               const float* __restrict__ W,
                                               const float* __restrict__ b,
                                               void* __restrict__ out_,
                                               int n_nodes) {
    __shared__ float Wl[D * D];
    __shared__ float bl[D];
    __shared__ float rows[ROWS_PER_BLOCK * RSTRIDE];

    int tid = threadIdx.x;

    const float4* W4 = (const float4*)W;
    float4* Wl4 = (float4*)Wl;
#pragma unroll
    for (int i = 0; i < 4; ++i) Wl4[tid + 256 * i] = W4[tid + 256 * i];
    if (tid < D / 4) ((float4*)bl)[tid] = ((const float4*)b)[tid];

    // stage 32 bf16 rows -> fp32 LDS (1 uint4 = 8 elems per thread)
    size_t row0 = (size_t)blockIdx.x * ROWS_PER_BLOCK;
    {
        uint4 u = hs[row0 * 8 + tid];
        float v[8];
        unpack8(v, u);
        int r = tid >> 3;            // 8 uint4 per 64-col row
        int col = (tid & 7) * 8;
        float* dstp = rows + r * RSTRIDE + col;
#pragma unroll
        for (int j = 0; j < 8; ++j) dstp[j] = v[j];
    }
    __syncthreads();

    int lane = tid & 63;
    int w = tid >> 6;

    float acc[8];
#pragma unroll
    for (int r = 0; r < 8; ++r) acc[r] = bl[lane];

#pragma unroll
    for (int k = 0; k < D; ++k) {
        float wv = Wl[k * D + lane];
#pragma unroll
        for (int r = 0; r < 8; ++r)
            acc[r] = fmaf(rows[(w * 8 + r) * RSTRIDE + k], wv, acc[r]);
    }

#pragma unroll
    for (int r = 0; r < 8; ++r) {
        float v = acc[r] > 0.0f ? acc[r] : 0.0f;
        size_t idx = (row0 + (size_t)w * 8 + r) * D + lane;
        if (BF16OUT) ((ushort_t*)out_)[idx] = f2bf(v);
        else         ((float*)out_)[idx] = v;
    }
}

extern "C" void kernel_launch(void* const* d_in, const int* in_sizes, int n_in,
                              void* d_out, int out_size, void* d_ws, size_t ws_size,
                              hipStream_t stream) {
    const float* x   = (const float*)d_in[0];
    const int*   src = (const int*)d_in[1];
    const int*   dst = (const int*)d_in[2];
    const float* W1  = (const float*)d_in[3];
    const float* b1  = (const float*)d_in[4];
    const float* W2  = (const float*)d_in[5];
    const float* b2  = (const float*)d_in[6];
    float* out = (float*)d_out;

    const int n_nodes = in_sizes[0] / D;
    const int n_edges = in_sizes[1];
    const int nch = (n_edges + CHSZ - 1) / CHSZ;     // 196
    const int nbs = (n_nodes + NPBS - 1) / NPBS;     // 196

    // workspace: Ab(bf16) | hb(bf16) | offs | sstart | total | hist | tmp | esrc
    ushort_t* Ab     = (ushort_t*)d_ws;                       // n_nodes*64 bf16
    ushort_t* hb     = Ab + (size_t)n_nodes * D;              // n_nodes*64 bf16
    int*      offs   = (int*)(hb + (size_t)n_nodes * D);      // n_nodes+1
    int*      sstart = offs + (n_nodes + 1);                  // nbs+1
    int*      total  = sstart + (nbs + 1);                    // nbs
    int*      hist   = total + nbs;                           // nbs*nch
    unsigned* tmp    = (unsigned*)(hist + (size_t)nbs * nch); // n_edges
    int*      esrc   = (int*)(tmp + n_edges);                 // n_edges

    const int agg_blocks = (n_nodes * 4 + 127) / 128;
    const int mlp_blocks = (n_nodes + ROWS_PER_BLOCK - 1) / ROWS_PER_BLOCK;
    const int cvt_blocks = (n_nodes * (D / 4) + 255) / 256;

    // ---- CSR build ----
    to_bf16z<<<cvt_blocks, 256, 0, stream>>>((const float4*)x, (uint2*)hb,
                                             n_nodes * (D / 4), total, nbs);
    k1_hist<<<nch, 256, 0, stream>>>(dst, hist, total, n_edges, nch, nbs);
    k2c_rowscan<<<nbs, 256, 0, stream>>>(hist, total, sstart, nch, nbs, n_edges);
    k3_scatter<<<nch, 256, 0, stream>>>(src, dst, hist, tmp, n_edges, nch, nbs);
    k4_fine<<<nbs, 256, 0, stream>>>(tmp, sstart, esrc, offs, n_nodes);

    // ---- layer 1: agg(xb) -> Ab; mlp(Ab) -> hb (bf16 h1) ----
    gin_agg_bf<<<agg_blocks, 128, 0, stream>>>((const uint4*)hb, offs, esrc,
                                               (uint4*)Ab, n_nodes);
    gin_mlp<true><<<mlp_blocks, 256, 0, stream>>>((const uint4*)Ab, W1, b1,
                                                  hb, n_nodes);

    // ---- layer 2: agg(h1b) -> Ab; mlp(Ab) -> out (fp32) ----
    gin_agg_bf<<<agg_blocks, 128, 0, stream>>>((const uint4*)hb, offs, esrc,
                                               (uint4*)Ab, n_nodes);
    gin_mlp<false><<<mlp_blocks, 256, 0, stream>>>((const uint4*)Ab, W2, b2,
                                                   out, n_nodes);
}

// Round 12
// 186.655 us; speedup vs baseline: 7.6057x; 1.0257x over previous
//
#include <hip/hip_runtime.h>
#include <hip/hip_bf16.h>

// 2-layer GIN, pull-mode aggregation, bf16 feature AND bf16 agg matrices.
//   aggb = bf16( f32(hb[n]) + sum f32(hb[src]) );  h' = relu(agg @ W + b)
// R12: build-kernel parallelism — CHSZ 4096 (391 chunks), 512-thread
// k1/k3/k4 (R11 profile: k3 at 0.8 TB/s on 196 blocks = issue-bound,
// not bandwidth-bound). Agg (R11: 8x unroll, pre-scaled esrc) unchanged.
// Requires n_nodes <= 131072 (18-bit src pack, 256-bucket scans).

#define D 64
#define ROWS_PER_BLOCK 32
#define CHSZ 4096      // edges per chunk (k1/k3)
#define NPBS 512       // nodes per super-bucket
#define SBSHIFT 9      // log2(NPBS)
#define MAXNBS 256     // static cap on #super-buckets (n_nodes <= 131072)
#define MAXNCH 512     // static cap on #chunks in k2c (n_edges <= 2.1M)

typedef unsigned short ushort_t;

__device__ inline unsigned short f2bf(float f) {   // RNE round to bf16
    unsigned u = __float_as_uint(f);
    return (unsigned short)((u + 0x7fff + ((u >> 16) & 1)) >> 16);
}

// acc[0..7] += 8 bf16 unpacked from one uint4
__device__ inline void acc8(float* acc, uint4 v) {
    acc[0] += __uint_as_float(v.x << 16);
    acc[1] += __uint_as_float(v.x & 0xffff0000u);
    acc[2] += __uint_as_float(v.y << 16);
    acc[3] += __uint_as_float(v.y & 0xffff0000u);
    acc[4] += __uint_as_float(v.z << 16);
    acc[5] += __uint_as_float(v.z & 0xffff0000u);
    acc[6] += __uint_as_float(v.w << 16);
    acc[7] += __uint_as_float(v.w & 0xffff0000u);
}

// 8 floats from one uint4 of packed bf16
__device__ inline void unpack8(float* v, uint4 u) {
    v[0] = __uint_as_float(u.x << 16); v[1] = __uint_as_float(u.x & 0xffff0000u);
    v[2] = __uint_as_float(u.y << 16); v[3] = __uint_as_float(u.y & 0xffff0000u);
    v[4] = __uint_as_float(u.z << 16); v[5] = __uint_as_float(u.z & 0xffff0000u);
    v[6] = __uint_as_float(u.w << 16); v[7] = __uint_as_float(u.w & 0xffff0000u);
}

// ---------------- CSR build ----------------

// fp32 -> bf16 conversion; block 0 also zeros the bucket totals.
__global__ __launch_bounds__(256) void to_bf16z(const float4* __restrict__ in,
                                                uint2* __restrict__ out, int n4,
                                                int* __restrict__ total, int nbs) {
    int i = blockIdx.x * 256 + threadIdx.x;
    if (blockIdx.x == 0)
        for (int j = threadIdx.x; j < nbs; j += 256) total[j] = 0;
    if (i >= n4) return;
    float4 v = in[i];
    out[i] = make_uint2((unsigned)f2bf(v.x) | ((unsigned)f2bf(v.y) << 16),
                        (unsigned)f2bf(v.z) | ((unsigned)f2bf(v.w) << 16));
}

// Per-chunk LDS histogram over super-buckets; accumulates per-bucket totals.
__global__ __launch_bounds__(512) void k1_hist(const int* __restrict__ dst,
                                               int* __restrict__ hist,
                                               int* __restrict__ total,
                                               int n_edges, int nch, int nbs) {
    __shared__ int lh[MAXNBS];
    for (int i = threadIdx.x; i < nbs; i += 512) lh[i] = 0;
    __syncthreads();
    int base = blockIdx.x * CHSZ;
    int lim = min(CHSZ, n_edges - base);
    for (int k = threadIdx.x; k < lim; k += 512)
        atomicAdd(&lh[dst[base + k] >> SBSHIFT], 1);
    __syncthreads();
    for (int i = threadIdx.x; i < nbs; i += 512) {
        int v = lh[i];
        hist[i * nch + blockIdx.x] = v;   // bucket-major
        if (v) atomicAdd(&total[i], v);
    }
}

// One block per bucket: (a) block-local prefix over the <=256 bucket totals
// gives this bucket's base (k2b folded in); (b) exclusive scan of its
// chunk-count row (+ base), in place; writes sstart[b].
__global__ __launch_bounds__(256) void k2c_rowscan(int* __restrict__ hist,
                                                   const int* __restrict__ total,
                                                   int* __restrict__ sstart,
                                                   int nch, int nbs, int n_edges) {
    __shared__ int tt[256];
    __shared__ int t[MAXNCH];
    int b = blockIdx.x;
    int tid = threadIdx.x;

    // (a) inclusive Hillis scan of totals
    tt[tid] = (tid < nbs) ? total[tid] : 0;
    __syncthreads();
    for (int off = 1; off < 256; off <<= 1) {
        int v = (tid >= off) ? tt[tid - off] : 0;
        __syncthreads();
        tt[tid] += v;
        __syncthreads();
    }
    int base = (b == 0) ? 0 : tt[b - 1];
    if (tid == 0) {
        sstart[b] = base;
        if (b == 0) sstart[nbs] = n_edges;
    }

    // (b) row scan
    int* row = hist + (size_t)b * nch;
    int nround = (nch + 255) & ~255;
    for (int i = tid; i < nround; i += 256) t[i] = (i < nch) ? row[i] : 0;
    __syncthreads();
    for (int off = 1; off < nround; off <<= 1) {
        int v[MAXNCH / 256];
        for (int i = tid, j = 0; i < nround; i += 256, ++j)
            v[j] = (i >= off) ? t[i - off] : 0;
        __syncthreads();
        for (int i = tid, j = 0; i < nround; i += 256, ++j) t[i] += v[j];
        __syncthreads();
    }
    for (int i = tid; i < nch; i += 256)
        row[i] = base + ((i == 0) ? 0 : t[i - 1]);
}

__global__ __launch_bounds__(512) void k3_scatter(const int* __restrict__ src,
                                                  const int* __restrict__ dst,
                                                  const int* __restrict__ hist,
                                                  unsigned* __restrict__ tmp,
                                                  int n_edges, int nch, int nbs) {
    __shared__ int lcur[MAXNBS];
    int c = blockIdx.x;
    for (int i = threadIdx.x; i < nbs; i += 512) lcur[i] = hist[i * nch + c];
    __syncthreads();
    int base = c * CHSZ;
    int lim = min(CHSZ, n_edges - base);
    for (int k = threadIdx.x; k < lim; k += 512) {
        int d = dst[base + k];
        int s = src[base + k];
        int pos = atomicAdd(&lcur[d >> SBSHIFT], 1);
        tmp[pos] = ((unsigned)(d & (NPBS - 1)) << 18) | (unsigned)s;
    }
}

// One WG (512 thr) per super-bucket: node-level counting sort in a WG-owned
// window. esrc entries PRE-SCALED: value = src * 8 (uint4 row base).
__global__ __launch_bounds__(512) void k4_fine(const unsigned* __restrict__ tmp,
                                               const int* __restrict__ sstart,
                                               int* __restrict__ esrc,
                                               int* __restrict__ offs,
                                               int n_nodes) {
    __shared__ int lcnt[NPBS];
    __shared__ int lcur[NPBS];
    __shared__ int tsum[256];

    int b = blockIdx.x;
    int tid = threadIdx.x;
    int base = sstart[b];
    int cnt = sstart[b + 1] - base;

    lcnt[tid] = 0;
    __syncthreads();

    for (int i = tid; i < cnt; i += 512)
        atomicAdd(&lcnt[tmp[base + i] >> 18], 1);
    __syncthreads();

    // pair-based exclusive scan of 512 counts by the first 256 threads
    int a0 = 0, a1 = 0;
    if (tid < 256) {
        a0 = lcnt[2 * tid];
        a1 = lcnt[2 * tid + 1];
        tsum[tid] = a0 + a1;
    }
    __syncthreads();
    for (int off = 1; off < 256; off <<= 1) {
        int v = 0;
        if (tid < 256 && tid >= off) v = tsum[tid - off];
        __syncthreads();
        if (tid < 256) tsum[tid] += v;
        __syncthreads();
    }
    if (tid < 256) {
        int ex = (tid == 0) ? 0 : tsum[tid - 1];
        lcur[2 * tid] = ex;
        lcur[2 * tid + 1] = ex + a0;
        int node = b * NPBS + 2 * tid;
        if (node <= n_nodes) offs[node] = base + ex;
        if (node + 1 <= n_nodes) offs[node + 1] = base + ex + a0;
    }
    __syncthreads();

    for (int i = tid; i < cnt; i += 512) {
        unsigned p = tmp[base + i];
        int pos = atomicAdd(&lcur[p >> 18], 1);
        esrc[base + pos] = (int)((p & 0x3FFFFu) << 3);   // src*8
    }
}

// ---------------- per-layer kernels ----------------

// Pull aggregation over bf16 matrix: 4 lanes/node, lane c owns bf16 cols
// [c*16, c*16+16) = 2 uint4. Edge loop unrolled 8x (16 uint4 in flight).
// acc starts at hb[n] (self term, eps=0). Output agg is bf16.
__global__ __launch_bounds__(128) void gin_agg_bf(const uint4* __restrict__ hb,
                                                  const int* __restrict__ offs,
                                                  const int* __restrict__ esrc,
                                                  uint4* __restrict__ aggb,
                                                  int n_nodes) {
    int t = blockIdx.x * 128 + threadIdx.x;
    int n = t >> 2;
    if (n >= n_nodes) return;
    int c2 = (t & 3) * 2;
    const uint4* selfp = hb + (size_t)n * 8 + c2;   // row = 8 uint4 (128 B)
    float acc[16];
#pragma unroll
    for (int j = 0; j < 16; ++j) acc[j] = 0.0f;
    {
        uint4 s0 = selfp[0], s1 = selfp[1];
        acc8(acc, s0); acc8(acc + 8, s1);
    }

    int i = offs[n];
    int end = offs[n + 1];

    for (; i + 8 <= end; i += 8) {
        uint4 v[16];
#pragma unroll
        for (int j = 0; j < 8; ++j) {
            const uint4* r = hb + (size_t)(unsigned)esrc[i + j] + c2;
            v[2 * j]     = r[0];
            v[2 * j + 1] = r[1];
        }
#pragma unroll
        for (int j = 0; j < 8; ++j) {
            acc8(acc, v[2 * j]);
            acc8(acc + 8, v[2 * j + 1]);
        }
    }
    if (i + 4 <= end) {
        uint4 v[8];
#pragma unroll
        for (int j = 0; j < 4; ++j) {
            const uint4* r = hb + (size_t)(unsigned)esrc[i + j] + c2;
            v[2 * j]     = r[0];
            v[2 * j + 1] = r[1];
        }
#pragma unroll
        for (int j = 0; j < 4; ++j) {
            acc8(acc, v[2 * j]);
            acc8(acc + 8, v[2 * j + 1]);
        }
        i += 4;
    }
    for (; i < end; ++i) {
        const uint4* r = hb + (size_t)(unsigned)esrc[i] + c2;
        uint4 a = r[0], b = r[1];
        acc8(acc, a); acc8(acc + 8, b);
    }

    uint4 o0, o1;
    o0.x = (unsigned)f2bf(acc[0])  | ((unsigned)f2bf(acc[1])  << 16);
    o0.y = (unsigned)f2bf(acc[2])  | ((unsigned)f2bf(acc[3])  << 16);
    o0.z = (unsigned)f2bf(acc[4])  | ((unsigned)f2bf(acc[5])  << 16);
    o0.w = (unsigned)f2bf(acc[6])  | ((unsigned)f2bf(acc[7])  << 16);
    o1.x = (unsigned)f2bf(acc[8])  | ((unsigned)f2bf(acc[9])  << 16);
    o1.y = (unsigned)f2bf(acc[10]) | ((unsigned)f2bf(acc[11]) << 16);
    o1.z = (unsigned)f2bf(acc[12]) | ((unsigned)f2bf(acc[13]) << 16);
    o1.w = (unsigned)f2bf(acc[14]) | ((unsigned)f2bf(acc[15]) << 16);
    aggb[(size_t)n * 8 + c2]     = o0;
    aggb[(size_t)n * 8 + c2 + 1] = o1;
}

// out = relu(hs @ W + b); hs is bf16 (uint4-packed), staged to fp32 LDS.
#define RSTRIDE (D + 4)   // padded LDS row stride (bank-spread)
template <bool BF16OUT>
__global__ __launch_bounds__(256) void gin_mlp(const uint4* __restrict__ hs,
                                               const float* __restrict__ W,
                                               const float* __restrict__ b,
                                               void* __restrict__ out_,
                                               int n_nodes) {
    __shared__ float Wl[D * D];
    __shared__ float bl[D];
    __shared__ float rows[ROWS_PER_BLOCK * RSTRIDE];

    int tid = threadIdx.x;

    const float4* W4 = (const float4*)W;
    float4* Wl4 = (float4*)Wl;
#pragma unroll
    for (int i = 0; i < 4; ++i) Wl4[tid + 256 * i] = W4[tid + 256 * i];
    if (tid < D / 4) ((float4*)bl)[tid] = ((const float4*)b)[tid];

    // stage 32 bf16 rows -> fp32 LDS (1 uint4 = 8 elems per thread)
    size_t row0 = (size_t)blockIdx.x * ROWS_PER_BLOCK;
    {
        uint4 u = hs[row0 * 8 + tid];
        float v[8];
        unpack8(v, u);
        int r = tid >> 3;            // 8 uint4 per 64-col row
        int col = (tid & 7) * 8;
        float* dstp = rows + r * RSTRIDE + col;
#pragma unroll
        for (int j = 0; j < 8; ++j) dstp[j] = v[j];
    }
    __syncthreads();

    int lane = tid & 63;
    int w = tid >> 6;

    float acc[8];
#pragma unroll
    for (int r = 0; r < 8; ++r) acc[r] = bl[lane];

#pragma unroll
    for (int k = 0; k < D; ++k) {
        float wv = Wl[k * D + lane];
#pragma unroll
        for (int r = 0; r < 8; ++r)
            acc[r] = fmaf(rows[(w * 8 + r) * RSTRIDE + k], wv, acc[r]);
    }

#pragma unroll
    for (int r = 0; r < 8; ++r) {
        float v = acc[r] > 0.0f ? acc[r] : 0.0f;
        size_t idx = (row0 + (size_t)w * 8 + r) * D + lane;
        if (BF16OUT) ((ushort_t*)out_)[idx] = f2bf(v);
        else         ((float*)out_)[idx] = v;
    }
}

extern "C" void kernel_launch(void* const* d_in, const int* in_sizes, int n_in,
                              void* d_out, int out_size, void* d_ws, size_t ws_size,
                              hipStream_t stream) {
    const float* x   = (const float*)d_in[0];
    const int*   src = (const int*)d_in[1];
    const int*   dst = (const int*)d_in[2];
    const float* W1  = (const float*)d_in[3];
    const float* b1  = (const float*)d_in[4];
    const float* W2  = (const float*)d_in[5];
    const float* b2  = (const float*)d_in[6];
    float* out = (float*)d_out;

    const int n_nodes = in_sizes[0] / D;
    const int n_edges = in_sizes[1];
    const int nch = (n_edges + CHSZ - 1) / CHSZ;     // 391
    const int nbs = (n_nodes + NPBS - 1) / NPBS;     // 196

    // workspace: Ab(bf16) | hb(bf16) | offs | sstart | total | hist | tmp | esrc
    ushort_t* Ab     = (ushort_t*)d_ws;                       // n_nodes*64 bf16
    ushort_t* hb     = Ab + (size_t)n_nodes * D;              // n_nodes*64 bf16
    int*      offs   = (int*)(hb + (size_t)n_nodes * D);      // n_nodes+1
    int*      sstart = offs + (n_nodes + 1);                  // nbs+1
    int*      total  = sstart + (nbs + 1);                    // nbs
    int*      hist   = total + nbs;                           // nbs*nch
    unsigned* tmp    = (unsigned*)(hist + (size_t)nbs * nch); // n_edges
    int*      esrc   = (int*)(tmp + n_edges);                 // n_edges

    const int agg_blocks = (n_nodes * 4 + 127) / 128;
    const int mlp_blocks = (n_nodes + ROWS_PER_BLOCK - 1) / ROWS_PER_BLOCK;
    const int cvt_blocks = (n_nodes * (D / 4) + 255) / 256;

    // ---- CSR build ----
    to_bf16z<<<cvt_blocks, 256, 0, stream>>>((const float4*)x, (uint2*)hb,
                                             n_nodes * (D / 4), total, nbs);
    k1_hist<<<nch, 512, 0, stream>>>(dst, hist, total, n_edges, nch, nbs);
    k2c_rowscan<<<nbs, 256, 0, stream>>>(hist, total, sstart, nch, nbs, n_edges);
    k3_scatter<<<nch, 512, 0, stream>>>(src, dst, hist, tmp, n_edges, nch, nbs);
    k4_fine<<<nbs, 512, 0, stream>>>(tmp, sstart, esrc, offs, n_nodes);

    // ---- layer 1: agg(xb) -> Ab; mlp(Ab) -> hb (bf16 h1) ----
    gin_agg_bf<<<agg_blocks, 128, 0, stream>>>((const uint4*)hb, offs, esrc,
                                               (uint4*)Ab, n_nodes);
    gin_mlp<true><<<mlp_blocks, 256, 0, stream>>>((const uint4*)Ab, W1, b1,
                                                  hb, n_nodes);

    // ---- layer 2: agg(h1b) -> Ab; mlp(Ab) -> out (fp32) ----
    gin_agg_bf<<<agg_blocks, 128, 0, stream>>>((const uint4*)hb, offs, esrc,
                                               (uint4*)Ab, n_nodes);
    gin_mlp<false><<<mlp_blocks, 256, 0, stream>>>((const uint4*)Ab, W2, b2,
                                                   out, n_nodes);
}